// Round 8
// baseline (84.537 us; speedup 1.0000x reference)
//
#include <hip/hip_runtime.h>
#include <hip/hip_bf16.h>

#define NB 4
#define NN 2048
#define NF 256
#define LOG2E 1.4426950408889634f

using bf16x8 = __attribute__((ext_vector_type(8))) short;
using f32x4  = __attribute__((ext_vector_type(4))) float;

__device__ __forceinline__ short f2bf(float f) {
    unsigned u = __float_as_uint(f);
    u += 0x7fffu + ((u >> 16) & 1u);   // RNE, finite inputs only
    return (short)(u >> 16);
}
__device__ __forceinline__ unsigned enc_ord(float f) {
    unsigned u = __float_as_uint(f);
    return (u & 0x80000000u) ? ~u : (u | 0x80000000u);
}
__device__ __forceinline__ float dec_ord(unsigned u) {
    unsigned i = (u & 0x80000000u) ? (u & 0x7fffffffu) : ~u;
    return __uint_as_float(i);
}
__device__ __forceinline__ void gll16(const void* g, void* l) {
    __builtin_amdgcn_global_load_lds(
        (const __attribute__((address_space(1))) unsigned int*)g,
        (__attribute__((address_space(3))) unsigned int*)l, 16, 0, 0);
}

// ---- prep: W->W^T bf16, maxfd init (tiny) ----
__global__ __launch_bounds__(256) void prep_kernel(
    const float* __restrict__ W, short* __restrict__ WT, unsigned* __restrict__ maxfd)
{
    const int blk = blockIdx.x, tid = threadIdx.x;
    if (blk < (NF*NF)/256) {
        int t = blk*256 + tid;
        WT[t] = f2bf(W[(t & 255)*NF + (t >> 8)]);   // WT[g][f] = W[f][g]
    } else if (tid < NB) {
        maxfd[tid] = 0u;
    }
}

// ---- work2: blocks [0,4096) = adj->bitmask pack; [4096,4608) = h GEMM ----
__global__ __launch_bounds__(256,4) void work2_kernel(
    const int* __restrict__ adj, unsigned short* __restrict__ adjB16,
    const float* __restrict__ x, const short* __restrict__ WT, const float* __restrict__ a,
    short* __restrict__ hT, float* __restrict__ fs2, float* __restrict__ fd2,
    unsigned* __restrict__ maxfd)
{
    if (blockIdx.x < 4096) {                // pack: 1M threads x 16 ints (64 B each)
        const int g = blockIdx.x*256 + threadIdx.x;
        const int4* p = (const int4*)(adj + (size_t)g*16);
        int4 v0 = p[0], v1 = p[1], v2 = p[2], v3 = p[3];
        unsigned m = 0;
        m |= (v0.x>0)<<0;  m |= (v0.y>0)<<1;  m |= (v0.z>0)<<2;  m |= (v0.w>0)<<3;
        m |= (v1.x>0)<<4;  m |= (v1.y>0)<<5;  m |= (v1.z>0)<<6;  m |= (v1.w>0)<<7;
        m |= (v2.x>0)<<8;  m |= (v2.y>0)<<9;  m |= (v2.z>0)<<10; m |= (v2.w>0)<<11;
        m |= (v3.x>0)<<12; m |= (v3.y>0)<<13; m |= (v3.z>0)<<14; m |= (v3.w>0)<<15;
        adjB16[g] = (unsigned short)m;
        return;
    }
    // ---- h = x@W (bf16 MFMA, K-pipelined) ----
    __shared__ float fs_l[16], fd_l[16];
    const int hb = blockIdx.x - 4096;
    const int w  = threadIdx.x >> 6;
    const int l  = threadIdx.x & 63;
    const int lr = l & 15, lg = l >> 4;
    const int b  = hb >> 7;
    const int ib = (hb & 127) * 16;

    if (threadIdx.x < 16) { fs_l[threadIdx.x] = 0.f; fd_l[threadIdx.x] = 0.f; }
    __syncthreads();

    f32x4 acc[4];
    #pragma unroll
    for (int t = 0; t < 4; t++) acc[t] = (f32x4){0.f,0.f,0.f,0.f};

    const float* xrow = x + (size_t)(b*NN + ib + lr) * NF + 8*lg;
    const short* wtp  = WT + (size_t)(w*64 + lr) * NF + 8*lg;

    float4 xa[2][2]; bf16x8 bfr[2][4];
    xa[0][0] = *(const float4*)(xrow);
    xa[0][1] = *(const float4*)(xrow + 4);
    #pragma unroll
    for (int nt = 0; nt < 4; nt++) bfr[0][nt] = *(const bf16x8*)(wtp + nt*16*NF);

    #pragma unroll
    for (int ks = 0; ks < 8; ks++) {
        const int cur = ks & 1;
        if (ks < 7) {
            const int nxt = cur ^ 1;
            xa[nxt][0] = *(const float4*)(xrow + (ks+1)*32);
            xa[nxt][1] = *(const float4*)(xrow + (ks+1)*32 + 4);
            #pragma unroll
            for (int nt = 0; nt < 4; nt++)
                bfr[nxt][nt] = *(const bf16x8*)(wtp + nt*16*NF + (ks+1)*32);
        }
        bf16x8 af;
        af[0]=f2bf(xa[cur][0].x); af[1]=f2bf(xa[cur][0].y);
        af[2]=f2bf(xa[cur][0].z); af[3]=f2bf(xa[cur][0].w);
        af[4]=f2bf(xa[cur][1].x); af[5]=f2bf(xa[cur][1].y);
        af[6]=f2bf(xa[cur][1].z); af[7]=f2bf(xa[cur][1].w);
        #pragma unroll
        for (int nt = 0; nt < 4; nt++)
            acc[nt] = __builtin_amdgcn_mfma_f32_16x16x32_bf16(af, bfr[cur][nt], acc[nt], 0, 0, 0);
    }

    float fsv[4] = {0,0,0,0}, fdv[4] = {0,0,0,0};
    #pragma unroll
    for (int nt = 0; nt < 4; nt++) {
        int g = w*64 + nt*16 + lr;
        float as = a[g], ad = a[NF + g];
        short4 hv;
        hv.x = f2bf(acc[nt][0]); hv.y = f2bf(acc[nt][1]);
        hv.z = f2bf(acc[nt][2]); hv.w = f2bf(acc[nt][3]);
        *(short4*)(hT + ((size_t)(b*NF + g))*NN + ib + lg*4) = hv;
        #pragma unroll
        for (int r = 0; r < 4; r++) { fsv[r] += acc[nt][r]*as; fdv[r] += acc[nt][r]*ad; }
    }
    #pragma unroll
    for (int mask = 1; mask < 16; mask <<= 1) {
        #pragma unroll
        for (int r = 0; r < 4; r++) {
            fsv[r] += __shfl_xor(fsv[r], mask);
            fdv[r] += __shfl_xor(fdv[r], mask);
        }
    }
    if (lr == 0) {
        #pragma unroll
        for (int r = 0; r < 4; r++) {
            atomicAdd(&fs_l[lg*4 + r], fsv[r]);
            atomicAdd(&fd_l[lg*4 + r], fdv[r]);
        }
    }
    __syncthreads();
    if (threadIdx.x < 16) {
        float fsu = fs_l[threadIdx.x] * LOG2E;
        float fdu = fd_l[threadIdx.x] * LOG2E;
        fs2[b*NN + ib + threadIdx.x] = fsu;
        fd2[b*NN + ib + threadIdx.x] = fdu;
        float wm = fdu;
        #pragma unroll
        for (int m = 1; m < 16; m <<= 1) wm = fmaxf(wm, __shfl_xor(wm, m));
        if (threadIdx.x == 0) atomicMax(maxfd + b, enc_ord(wm));
    }
}

// ---- fused: masked softmax + att@h + elu ----
// grid 512 = 4b x 32 itile(64 rows) x 4 fq(64 f); 512 thr = 2 rowg x 4 kt waves.
// 8 groups x 2 steps (BK=256/fence). 2 slots x 32 KB; LOADP issued BEFORE
// STAGE_G so compiler's auto-vmcnt on prefetch regs doesn't drain staging;
// group-end vmcnt(12) protects S(g+1) with a full group of slack.
__global__ __launch_bounds__(512,4) void gat_fused(
    const short* __restrict__ hT, const unsigned char* __restrict__ adjB,
    const float* __restrict__ fs2, const float* __restrict__ fd2,
    const unsigned* __restrict__ maxfd, float* __restrict__ out)
{
    __shared__ __align__(16) char smem[66560];   // 2x32768 staging + 1KB ls
    float* ls = (float*)(smem + 65536);

    const int tid = threadIdx.x;
    const int w = tid >> 6, l = tid & 63, lr = l & 15, lg = l >> 4;
    const int kt = w & 3, rowg = w >> 2;
    const int blk = blockIdx.x;
    const int b = blk >> 7, rest = blk & 127;
    const int itile = rest >> 2, fq = rest & 3;
    const int i0 = itile * 64, f0 = fq * 64;

    const short* hTb = hT + (size_t)b * NF * NN + (size_t)f0 * NN;

    // staging source (inverse-XOR so linear gll dst + XOR read = identity)
    const int q1 = tid, sr1 = q1 >> 4, sc1 = (q1 & 15) ^ (sr1 & 15);
    const int q2 = 512 + tid, sr2 = q2 >> 4, sc2 = (q2 & 15) ^ (sr2 & 15);
    const short* sb1 = hTb + (size_t)sr1 * NN + sc1*8;
    const short* sb2 = hTb + (size_t)sr2 * NN + sc2*8;

    // per-row softmax constants (rows rowg*32 + {lr, lr+16}), log2-scaled
    const float mx2 = dec_ord(maxfd[b]);
    const int gi0 = b*NN + i0 + rowg*32 + lr;
    const float fsa = fs2[gi0], fsb = fs2[gi0 + 16];
    const float M0 = fmaxf(fsa + mx2, 0.f), M1 = fmaxf(fsb + mx2, 0.f);
    const float fsM0 = fsa - M0, nM0 = -M0;
    const float fsM1 = fsb - M1, nM1 = -M1;

    const unsigned char* ar0 = adjB + (size_t)gi0 * (NN/8) + kt*4 + lg;
    const unsigned char* ar1 = ar0 + 16*(NN/8);
    const float* fdp = fd2 + b*NN + kt*32 + lg*8;

    const int boff = lr*256 + (((kt*4 + lg) ^ lr) << 4);   // within 16KB sub-tile

    f32x4 acc[2][4];
    #pragma unroll
    for (int i = 0; i < 2; ++i)
        #pragma unroll
        for (int j = 0; j < 4; ++j) acc[i][j] = (f32x4){0.f,0.f,0.f,0.f};
    float lsum0 = 0.f, lsum1 = 0.f;

    auto STAGE_G = [&](int g2, int slot) {   // stage steps 2g2, 2g2+1 (4 gll/thread)
        char* base = smem + slot * 32768;
        const int wb = w << 10;              // wave-uniform base; HW adds lane*16
        gll16(sb1 + (2*g2    )*128, base + wb);
        gll16(sb2 + (2*g2    )*128, base + 8192  + wb);
        gll16(sb1 + (2*g2 + 1)*128, base + 16384 + wb);
        gll16(sb2 + (2*g2 + 1)*128, base + 24576 + wb);
    };
    auto LOADP = [&](int t, unsigned& m0, unsigned& m1, f32x4& fa, f32x4& fb) {
        m0 = ar0[t*16]; m1 = ar1[t*16];
        fa = *(const f32x4*)(fdp + t*128);
        fb = *(const f32x4*)(fdp + t*128 + 4);
    };
    auto BODY = [&](int t, int slot, unsigned m0, unsigned m1,
                    const f32x4& fa, const f32x4& fb) {
        const char* sb = smem + slot * 32768 + ((t & 1) << 14);
        bf16x8 b0 = *(const bf16x8*)(sb + boff);
        bf16x8 b1 = *(const bf16x8*)(sb + boff + 4096);
        bf16x8 b2 = *(const bf16x8*)(sb + boff + 8192);
        bf16x8 b3 = *(const bf16x8*)(sb + boff + 12288);
        float fdv[8] = {fa[0],fa[1],fa[2],fa[3],fb[0],fb[1],fb[2],fb[3]};
        float p0[8], p1[8];
        #pragma unroll
        for (int e = 0; e < 8; ++e) {
            float v0 = __builtin_amdgcn_exp2f(fmaxf(fsM0 + fdv[e], nM0));
            float v1 = __builtin_amdgcn_exp2f(fmaxf(fsM1 + fdv[e], nM1));
            v0 = (m0 & (1u << e)) ? v0 : 0.f;
            v1 = (m1 & (1u << e)) ? v1 : 0.f;
            lsum0 += v0; lsum1 += v1;
            p0[e] = v0;  p1[e] = v1;
        }
        union { bf16x8 v; unsigned u[4]; } a0u, a1u;
        #pragma unroll
        for (int d = 0; d < 4; ++d) {
            asm("v_cvt_pk_bf16_f32 %0, %1, %2" : "=v"(a0u.u[d]) : "v"(p0[2*d]), "v"(p0[2*d+1]));
            asm("v_cvt_pk_bf16_f32 %0, %1, %2" : "=v"(a1u.u[d]) : "v"(p1[2*d]), "v"(p1[2*d+1]));
        }
        acc[0][0] = __builtin_amdgcn_mfma_f32_16x16x32_bf16(a0u.v, b0, acc[0][0], 0, 0, 0);
        acc[1][0] = __builtin_amdgcn_mfma_f32_16x16x32_bf16(a1u.v, b0, acc[1][0], 0, 0, 0);
        acc[0][1] = __builtin_amdgcn_mfma_f32_16x16x32_bf16(a0u.v, b1, acc[0][1], 0, 0, 0);
        acc[1][1] = __builtin_amdgcn_mfma_f32_16x16x32_bf16(a1u.v, b1, acc[1][1], 0, 0, 0);
        acc[0][2] = __builtin_amdgcn_mfma_f32_16x16x32_bf16(a0u.v, b2, acc[0][2], 0, 0, 0);
        acc[1][2] = __builtin_amdgcn_mfma_f32_16x16x32_bf16(a1u.v, b2, acc[1][2], 0, 0, 0);
        acc[0][3] = __builtin_amdgcn_mfma_f32_16x16x32_bf16(a0u.v, b3, acc[0][3], 0, 0, 0);
        acc[1][3] = __builtin_amdgcn_mfma_f32_16x16x32_bf16(a1u.v, b3, acc[1][3], 0, 0, 0);
    };
    #define SBAR do { __builtin_amdgcn_sched_barrier(0); \
        __builtin_amdgcn_s_barrier(); \
        __builtin_amdgcn_sched_barrier(0); } while (0)
    #define FENCE12 do { __builtin_amdgcn_sched_barrier(0); \
        asm volatile("s_waitcnt vmcnt(12)" ::: "memory"); \
        __builtin_amdgcn_s_barrier(); \
        __builtin_amdgcn_sched_barrier(0); } while (0)

    unsigned mA0, mA1, mB0, mB1;
    f32x4 faA, fbA, faB, fbB;

    // prologue: S0 -> slot0; prefetch steps 0,1; S1 -> slot1 stays in flight
    STAGE_G(0, 0);
    LOADP(0, mA0, mA1, faA, fbA);
    LOADP(1, mB0, mB1, faB, fbB);
    STAGE_G(1, 1);
    __builtin_amdgcn_sched_barrier(0);
    asm volatile("s_waitcnt vmcnt(4)" ::: "memory");   // S0 + P(0,1) done; S1 in flight
    __builtin_amdgcn_s_barrier();
    __builtin_amdgcn_sched_barrier(0);

    for (int g = 0; g < 8; ++g) {
        BODY(2*g,     g & 1, mA0, mA1, faA, fbA);
        BODY(2*g + 1, g & 1, mB0, mB1, faB, fbB);
        SBAR;                                   // all reads of slot g&1 done block-wide
        if (g < 7) {
            LOADP(2*g + 2, mA0, mA1, faA, fbA); // prefetch BEFORE stage (vmcnt order)
            LOADP(2*g + 3, mB0, mB1, faB, fbB);
            if (g + 2 < 8) STAGE_G(g + 2, g & 1);
            FENCE12;                            // waits S(g+1); leaves P+S(g+2) in flight
        }
    }
    __syncthreads();

    // ---- epilogue ----
    lsum0 += __shfl_xor(lsum0, 16); lsum0 += __shfl_xor(lsum0, 32);
    lsum1 += __shfl_xor(lsum1, 16); lsum1 += __shfl_xor(lsum1, 32);
    if (l < 16) {
        ls[((rowg*2 + 0)*16 + lr)*4 + kt] = lsum0;
        ls[((rowg*2 + 1)*16 + lr)*4 + kt] = lsum1;
    }
    __syncthreads();

    float* red  = (float*)smem;                  // 16 KB each, alias staging (loop done)
    float* red2 = (float*)(smem + 16384);
    if (kt >= 2) {
        float* dst = (kt == 2) ? red : red2;
        #pragma unroll
        for (int mt = 0; mt < 2; ++mt)
            #pragma unroll
            for (int nt = 0; nt < 4; ++nt)
                #pragma unroll
                for (int r = 0; r < 4; ++r)
                    dst[rowg*2048 + (mt*16 + lg*4 + r)*64 + nt*16 + lr] = acc[mt][nt][r];
    }
    __syncthreads();
    if (kt < 2) {
        const float* srcp = (kt == 0) ? red : red2;
        #pragma unroll
        for (int mt = 0; mt < 2; ++mt)
            #pragma unroll
            for (int nt = 0; nt < 4; ++nt)
                #pragma unroll
                for (int r = 0; r < 4; ++r)
                    acc[mt][nt][r] += srcp[rowg*2048 + (mt*16 + lg*4 + r)*64 + nt*16 + lr];
    }
    __syncthreads();
    if (kt == 1) {
        #pragma unroll
        for (int mt = 0; mt < 2; ++mt)
            #pragma unroll
            for (int nt = 0; nt < 4; ++nt)
                #pragma unroll
                for (int r = 0; r < 4; ++r)
                    red[rowg*2048 + (mt*16 + lg*4 + r)*64 + nt*16 + lr] = acc[mt][nt][r];
    }
    __syncthreads();
    if (kt == 0) {
        float rv[2][4];
        #pragma unroll
        for (int mt = 0; mt < 2; ++mt)
            #pragma unroll
            for (int r = 0; r < 4; ++r) {
                int base = ((rowg*2 + mt)*16 + lg*4 + r)*4;
                float tot = ls[base] + ls[base+1] + ls[base+2] + ls[base+3];
                rv[mt][r] = tot > 0.f ? 1.f / tot : 0.f;
            }
        #pragma unroll
        for (int mt = 0; mt < 2; ++mt)
            #pragma unroll
            for (int nt = 0; nt < 4; ++nt)
                #pragma unroll
                for (int r = 0; r < 4; ++r) {
                    float v = acc[mt][nt][r]
                            + red[rowg*2048 + (mt*16 + lg*4 + r)*64 + nt*16 + lr];
                    v *= rv[mt][r];
                    v = v > 0.f ? v : expm1f(v);
                    int row = i0 + rowg*32 + mt*16 + lg*4 + r;
                    out[(size_t)(b*NN + row)*NF + f0 + nt*16 + lr] = v;
                }
    }
    #undef SBAR
    #undef FENCE12
}

extern "C" void kernel_launch(void* const* d_in, const int* in_sizes, int n_in,
                              void* d_out, int out_size, void* d_ws, size_t ws_size,
                              hipStream_t stream) {
    const float* x   = (const float*)d_in[0];
    const int*   adj = (const int*)d_in[1];
    const float* W   = (const float*)d_in[2];
    const float* a   = (const float*)d_in[3];
    float* out = (float*)d_out;
    char* ws = (char*)d_ws;

    short* WT       = (short*)(ws);                   // 128 KB
    short* hT       = (short*)(ws + 0x20000);         // 4 MB
    float* fs2      = (float*)(ws + 0x420000);        // 32 KB
    float* fd2      = (float*)(ws + 0x428000);        // 32 KB
    unsigned* maxfd = (unsigned*)(ws + 0x430000);     // 16 B
    unsigned short* adjB16 = (unsigned short*)(ws + 0x440000); // 2 MB

    prep_kernel<<<(NF*NF)/256 + 1, 256, 0, stream>>>(W, WT, maxfd);
    work2_kernel<<<4096 + 512, 256, 0, stream>>>(adj, adjB16, x, WT, a,
                                                 hT, fs2, fd2, maxfd);
    gat_fused<<<NB*128, 512, 0, stream>>>(hT, (const unsigned char*)adjB16,
                                          fs2, fd2, maxfd, out);
}